// Round 2
// baseline (997.082 us; speedup 1.0000x reference)
//
#include <hip/hip_runtime.h>

// ---------------------------------------------------------------------------
// GCN forward: h1 = relu(GCNConv(x, W1, b1)); h2 = relu(GCNConv(h1, W2, b2));
// out = h2 @ W_lin + b_lin
// N=100000, E=3200000, F_in=128, H=16, F_out=128 (sizes derived at runtime).
//
// NOTE: harness delivers integer inputs as int32 (contract: "integer ->
// const int*"), so edge_index is int32 [2*E], row 0 = src, row 1 = dst.
//
// Strategy:
//  - deg/dinv once (self-loop => deg >= 1).
//  - CSR by dst built per call in d_ws (histogram + 1-block scan + atomic fill).
//  - propagate(d) = dinv[d] * ( sum_{s in in(d)} g[s] + g[d] ),  g = (h@W)*dinv
//  - aggregation: 1 wave per node, 4 neighbor-groups x 16 feature lanes,
//    shfl_xor butterfly reduce. Deterministic (no fp32 atomics).
// ---------------------------------------------------------------------------

__global__ void k_hist_init(int* deg_cnt, int N) {
    int i = blockIdx.x * blockDim.x + threadIdx.x;
    if (i < N) deg_cnt[i] = 1;  // self-loop
}

__global__ void k_hist(const int* __restrict__ ei, int* deg_cnt, int E) {
    int e = blockIdx.x * blockDim.x + threadIdx.x;
    if (e < E) atomicAdd(&deg_cnt[ei[E + e]], 1);
}

__global__ void k_dinv(const int* deg_cnt, float* dinv, int N) {
    int i = blockIdx.x * blockDim.x + threadIdx.x;
    if (i < N) dinv[i] = rsqrtf((float)deg_cnt[i]);
}

// Single-block exclusive scan of (deg_cnt[i]-1) over N elements.
__global__ __launch_bounds__(1024) void k_scan(const int* deg_cnt, int* row_start,
                                               int* cursor, int N, int E) {
    __shared__ int s[1024];
    int t = threadIdx.x;
    int chunk = (N + 1023) >> 10;
    int beg = t * chunk;
    int end = min(beg + chunk, N);
    int sum = 0;
    for (int i = beg; i < end; ++i) sum += deg_cnt[i] - 1;
    s[t] = sum;
    __syncthreads();
    // Hillis-Steele inclusive scan over 1024 partials
    for (int off = 1; off < 1024; off <<= 1) {
        int v = (t >= off) ? s[t - off] : 0;
        __syncthreads();
        s[t] += v;
        __syncthreads();
    }
    int run = (t == 0) ? 0 : s[t - 1];
    for (int i = beg; i < end; ++i) {
        int dm1 = deg_cnt[i] - 1;
        row_start[i] = run;
        cursor[i]    = run;
        run += dm1;
    }
    if (t == 0) row_start[N] = E;
}

__global__ void k_fill(const int* __restrict__ ei, int* cursor, int* csr_src, int E) {
    int e = blockIdx.x * blockDim.x + threadIdx.x;
    if (e < E) {
        int s = ei[e];
        int d = ei[E + e];
        int pos = atomicAdd(&cursor[d], 1);
        csr_src[pos] = s;
    }
}

// g[n,:] = (x[n,:] @ W1) * dinv[n]    (128 -> 16), 16 nodes per 256-thread block
__global__ __launch_bounds__(256) void k_xform1(const float* __restrict__ x,
                                                const float* __restrict__ W1,
                                                const float* __restrict__ dinv,
                                                float* __restrict__ g, int N) {
    __shared__ float xs[16][129];   // +1 pad: avoid bank conflicts on node dim
    __shared__ float ws[128 * 16];
    int t = threadIdx.x;
    int n0 = blockIdx.x * 16;
    for (int idx = t; idx < 2048; idx += 256) ws[idx] = W1[idx];
    for (int idx = t; idx < 2048; idx += 256) {
        int r = idx >> 7, c = idx & 127;
        int n = n0 + r;
        xs[r][c] = (n < N) ? x[(long long)n * 128 + c] : 0.f;
    }
    __syncthreads();
    int node = t >> 4, f = t & 15;
    int n = n0 + node;
    if (n < N) {
        float sum = 0.f;
#pragma unroll
        for (int k = 0; k < 128; ++k) sum += xs[node][k] * ws[k * 16 + f];
        g[(long long)n * 16 + f] = sum * dinv[n];
    }
}

// h[d,:] = relu( dinv[d] * (sum_{s in row d} g[s,:] + g[d,:]) + bias )
// one wave per node: 4 neighbor groups x 16 feature lanes
__global__ __launch_bounds__(256) void k_aggr(const float* __restrict__ g,
                                              const int* __restrict__ row_start,
                                              const int* __restrict__ csr_src,
                                              const float* __restrict__ dinv,
                                              const float* __restrict__ bias,
                                              float* __restrict__ h, int N) {
    int wave = threadIdx.x >> 6;
    int lane = threadIdx.x & 63;
    int d = blockIdx.x * 4 + wave;
    if (d >= N) return;
    int grp = lane >> 4, f = lane & 15;
    int s0 = row_start[d], s1 = row_start[d + 1];
    float sum = 0.f;
    for (int i = s0 + grp; i < s1; i += 4) {
        int s = csr_src[i];
        sum += g[(long long)s * 16 + f];
    }
    sum += __shfl_xor(sum, 16);
    sum += __shfl_xor(sum, 32);
    if (grp == 0) {
        float v = dinv[d] * (sum + g[(long long)d * 16 + f]) + bias[f];
        h[(long long)d * 16 + f] = fmaxf(v, 0.f);
    }
}

// g[n,:] = (h[n,:] @ W2) * dinv[n]    (16 -> 16), one thread per output element
__global__ __launch_bounds__(256) void k_xform2(const float* __restrict__ h,
                                                const float* __restrict__ W2,
                                                const float* __restrict__ dinv,
                                                float* __restrict__ g, int N) {
    __shared__ float ws[256];
    int t = threadIdx.x;
    ws[t] = W2[t];
    __syncthreads();
    int idx = blockIdx.x * 256 + t;
    if (idx < N * 16) {
        int n = idx >> 4, f = idx & 15;
        float sum = 0.f;
#pragma unroll
        for (int k = 0; k < 16; ++k) sum += h[(long long)n * 16 + k] * ws[k * 16 + f];
        g[idx] = sum * dinv[n];
    }
}

// out[n,:] = h[n,:] @ W_lin + b_lin   (16 -> 128), 2 nodes per 256-thread block
__global__ __launch_bounds__(256) void k_final(const float* __restrict__ h,
                                               const float* __restrict__ Wl,
                                               const float* __restrict__ bl,
                                               float* __restrict__ out, int N) {
    __shared__ float ws[16 * 128];
    __shared__ float hs[2][16];
    int t = threadIdx.x;
    int n0 = blockIdx.x * 2;
    for (int idx = t; idx < 2048; idx += 256) ws[idx] = Wl[idx];
    if (t < 32) {
        int node = t >> 4, k = t & 15;
        int n = n0 + node;
        hs[node][k] = (n < N) ? h[(long long)n * 16 + k] : 0.f;
    }
    __syncthreads();
    int node = t >> 7, f = t & 127;
    int n = n0 + node;
    if (n < N) {
        float sum = bl[f];
#pragma unroll
        for (int k = 0; k < 16; ++k) sum += hs[node][k] * ws[k * 128 + f];
        out[(long long)n * 128 + f] = sum;
    }
}

extern "C" void kernel_launch(void* const* d_in, const int* in_sizes, int n_in,
                              void* d_out, int out_size, void* d_ws, size_t ws_size,
                              hipStream_t stream) {
    const float* x  = (const float*)d_in[0];
    const int*   ei = (const int*)d_in[1];     // int32 per harness contract
    const float* W1 = (const float*)d_in[2];
    const float* b1 = (const float*)d_in[3];
    const float* W2 = (const float*)d_in[4];
    const float* b2 = (const float*)d_in[5];
    const float* Wl = (const float*)d_in[6];
    const float* bl = (const float*)d_in[7];
    float*       out = (float*)d_out;

    const int N = in_sizes[0] / 128;
    const int E = in_sizes[1] / 2;

    // carve workspace (256B aligned)
    char* ws = (char*)d_ws;
    auto carve = [&](size_t bytes) {
        char* p = ws;
        ws += (bytes + 255) & ~(size_t)255;
        return p;
    };
    int*   deg_cnt   = (int*)carve((size_t)N * 4);
    float* dinv      = (float*)carve((size_t)N * 4);
    int*   row_start = (int*)carve((size_t)(N + 1) * 4);
    int*   cursor    = (int*)carve((size_t)N * 4);
    int*   csr_src   = (int*)carve((size_t)E * 4);
    float* gbuf      = (float*)carve((size_t)N * 16 * 4);
    float* hbuf      = (float*)carve((size_t)N * 16 * 4);
    (void)ws_size; (void)n_in; (void)out_size;

    const int TB = 256;
    // degree + dinv (shared by both layers)
    k_hist_init<<<(N + TB - 1) / TB, TB, 0, stream>>>(deg_cnt, N);
    k_hist<<<(E + TB - 1) / TB, TB, 0, stream>>>(ei, deg_cnt, E);
    k_dinv<<<(N + TB - 1) / TB, TB, 0, stream>>>(deg_cnt, dinv, N);
    // CSR by dst (shared by both layers)
    k_scan<<<1, 1024, 0, stream>>>(deg_cnt, row_start, cursor, N, E);
    k_fill<<<(E + TB - 1) / TB, TB, 0, stream>>>(ei, cursor, csr_src, E);
    // layer 1
    k_xform1<<<(N + 15) / 16, TB, 0, stream>>>(x, W1, dinv, gbuf, N);
    k_aggr<<<(N + 3) / 4, TB, 0, stream>>>(gbuf, row_start, csr_src, dinv, b1, hbuf, N);
    // layer 2
    k_xform2<<<(N * 16 + TB - 1) / TB, TB, 0, stream>>>(hbuf, W2, dinv, gbuf, N);
    k_aggr<<<(N + 3) / 4, TB, 0, stream>>>(gbuf, row_start, csr_src, dinv, b2, hbuf, N);
    // output projection
    k_final<<<(N + 1) / 2, TB, 0, stream>>>(hbuf, Wl, bl, out, N);
}

// Round 3
// 483.823 us; speedup vs baseline: 2.0608x; 2.0608x over previous
//
#include <hip/hip_runtime.h>

// ---------------------------------------------------------------------------
// GCN forward: h1 = relu(GCNConv(x, W1, b1)); h2 = relu(GCNConv(h1, W2, b2));
// out = h2 @ W_lin + b_lin
// N=100000, E=3200000, F_in=128, H=16, F_out=128 (sizes derived at runtime).
// edge_index arrives as int32 [2*E]: row 0 = src, row 1 = dst.
//
// CSR build = two-level binning (R3): bucket-count -> 1024-scan -> partition
// into bucket-contiguous (s,d) pair runs (write-amp ~1) -> per-bucket build
// (deg, dinv, row_start, csr scatter all block-local). Replaces the naive
// hist + single-block scan + global scatter fill whose WRITE_SIZE was 194 MB
// for a 12.8 MB payload (R2 profile).
// ---------------------------------------------------------------------------

#define NB_MAX     1024   // max buckets (LDS hist size)
#define NPB        128    // nodes per bucket (power of 2)
#define NPB_SHIFT  7
#define PART_TILE  8192   // edges per partition block

__global__ void k_zero_buckets(int* bucket_cnt) {
    bucket_cnt[threadIdx.x] = 0;
}

// Per-block LDS histogram of dst>>7, flushed once per block.
__global__ __launch_bounds__(256) void k_bucket_cnt(const int* __restrict__ ei,
                                                    int* __restrict__ bucket_cnt, int E) {
    __shared__ int h[NB_MAX];
    int t = threadIdx.x;
    for (int j = t; j < NB_MAX; j += 256) h[j] = 0;
    __syncthreads();
    for (int e = blockIdx.x * blockDim.x + t; e < E; e += gridDim.x * blockDim.x)
        atomicAdd(&h[ei[E + e] >> NPB_SHIFT], 1);
    __syncthreads();
    for (int j = t; j < NB_MAX; j += 256)
        if (h[j]) atomicAdd(&bucket_cnt[j], h[j]);
}

// Exclusive scan of 1024 bucket counts; init base + cursor.
__global__ __launch_bounds__(1024) void k_bucket_scan(const int* __restrict__ bucket_cnt,
                                                      int* __restrict__ bucket_base,
                                                      int* __restrict__ bucket_cur) {
    __shared__ int s[NB_MAX];
    int t = threadIdx.x;
    int v0 = bucket_cnt[t];
    s[t] = v0;
    __syncthreads();
    for (int off = 1; off < NB_MAX; off <<= 1) {
        int v = (t >= off) ? s[t - off] : 0;
        __syncthreads();
        s[t] += v;
        __syncthreads();
    }
    int excl = s[t] - v0;
    bucket_base[t] = excl;
    bucket_cur[t]  = excl;
}

// Partition edges into bucket-contiguous (src,dst) pair runs.
// One atomic run-reservation per (block,bucket); run writes are block-local
// and temporally tight -> ~1x write amplification.
__global__ __launch_bounds__(256) void k_partition(const int* __restrict__ ei,
                                                   int* __restrict__ bucket_cur,
                                                   int2* __restrict__ pairs, int E) {
    __shared__ int h[NB_MAX];    // pass1: local hist; pass2: local cursor
    __shared__ int rb[NB_MAX];   // run base (absolute) per bucket
    int t = threadIdx.x;
    int e0 = blockIdx.x * PART_TILE;
    for (int j = t; j < NB_MAX; j += 256) h[j] = 0;
    __syncthreads();
    for (int i = t; i < PART_TILE; i += 256) {
        int e = e0 + i;
        if (e < E) atomicAdd(&h[ei[E + e] >> NPB_SHIFT], 1);
    }
    __syncthreads();
    for (int j = t; j < NB_MAX; j += 256) {
        int c = h[j];
        rb[j] = c ? atomicAdd(&bucket_cur[j], c) : 0;
        h[j] = 0;
    }
    __syncthreads();
    for (int i = t; i < PART_TILE; i += 256) {
        int e = e0 + i;
        if (e < E) {
            int s = ei[e];
            int d = ei[E + e];
            int b = d >> NPB_SHIFT;
            int pos = rb[b] + atomicAdd(&h[b], 1);
            pairs[pos] = make_int2(s, d);
        }
    }
}

// One block per bucket: local deg hist -> local scan -> row_start/dinv/cursor,
// then scatter csr_src within the bucket's contiguous region.
__global__ __launch_bounds__(256) void k_build(const int2* __restrict__ pairs,
                                               const int* __restrict__ bucket_cnt,
                                               const int* __restrict__ bucket_base,
                                               int* __restrict__ row_start,
                                               float* __restrict__ dinv,
                                               int* __restrict__ csr_src, int N) {
    __shared__ int deg[NPB];
    __shared__ int scn[NPB];
    __shared__ int cur[NPB];
    int b = blockIdx.x, t = threadIdx.x;
    int n0 = b << NPB_SHIFT;
    int cnt  = bucket_cnt[b];
    int base = bucket_base[b];
    if (t < NPB) deg[t] = 0;
    __syncthreads();
    for (int i = t; i < cnt; i += 256)
        atomicAdd(&deg[pairs[base + i].y - n0], 1);
    __syncthreads();
    if (t < NPB) scn[t] = deg[t];
    __syncthreads();
    for (int off = 1; off < NPB; off <<= 1) {
        int v = (t < NPB && t >= off) ? scn[t - off] : 0;
        __syncthreads();
        if (t < NPB) scn[t] += v;
        __syncthreads();
    }
    if (t < NPB) {
        int n = n0 + t;
        if (n < N) {
            int excl = scn[t] - deg[t];
            row_start[n] = base + excl;
            cur[t]       = base + excl;
            dinv[n]      = rsqrtf((float)(deg[t] + 1));  // +1 self-loop
        }
    }
    if (t == 0 && b == gridDim.x - 1) row_start[N] = base + cnt;
    __syncthreads();
    for (int i = t; i < cnt; i += 256) {
        int2 p = pairs[base + i];
        int pos = atomicAdd(&cur[p.y - n0], 1);
        csr_src[pos] = p.x;
    }
}

// g[n,:] = (x[n,:] @ W1) * dinv[n]    (128 -> 16), 16 nodes per 256-thread block
__global__ __launch_bounds__(256) void k_xform1(const float* __restrict__ x,
                                                const float* __restrict__ W1,
                                                const float* __restrict__ dinv,
                                                float* __restrict__ g, int N) {
    __shared__ float xs[16][129];
    __shared__ float ws[128 * 16];
    int t = threadIdx.x;
    int n0 = blockIdx.x * 16;
    for (int idx = t; idx < 2048; idx += 256) ws[idx] = W1[idx];
    for (int idx = t; idx < 2048; idx += 256) {
        int r = idx >> 7, c = idx & 127;
        int n = n0 + r;
        xs[r][c] = (n < N) ? x[(long long)n * 128 + c] : 0.f;
    }
    __syncthreads();
    int node = t >> 4, f = t & 15;
    int n = n0 + node;
    if (n < N) {
        float sum = 0.f;
#pragma unroll
        for (int k = 0; k < 128; ++k) sum += xs[node][k] * ws[k * 16 + f];
        g[(long long)n * 16 + f] = sum * dinv[n];
    }
}

// h[d,:] = relu( dinv[d] * (sum_{s in row d} g[s,:] + g[d,:]) + bias )
__global__ __launch_bounds__(256) void k_aggr(const float* __restrict__ g,
                                              const int* __restrict__ row_start,
                                              const int* __restrict__ csr_src,
                                              const float* __restrict__ dinv,
                                              const float* __restrict__ bias,
                                              float* __restrict__ h, int N) {
    int wave = threadIdx.x >> 6;
    int lane = threadIdx.x & 63;
    int d = blockIdx.x * 4 + wave;
    if (d >= N) return;
    int grp = lane >> 4, f = lane & 15;
    int s0 = row_start[d], s1 = row_start[d + 1];
    float sum = 0.f;
    for (int i = s0 + grp; i < s1; i += 4) {
        int s = csr_src[i];
        sum += g[(long long)s * 16 + f];
    }
    sum += __shfl_xor(sum, 16);
    sum += __shfl_xor(sum, 32);
    if (grp == 0) {
        float v = dinv[d] * (sum + g[(long long)d * 16 + f]) + bias[f];
        h[(long long)d * 16 + f] = fmaxf(v, 0.f);
    }
}

// g[n,:] = (h[n,:] @ W2) * dinv[n]    (16 -> 16)
__global__ __launch_bounds__(256) void k_xform2(const float* __restrict__ h,
                                                const float* __restrict__ W2,
                                                const float* __restrict__ dinv,
                                                float* __restrict__ g, int N) {
    __shared__ float ws[256];
    int t = threadIdx.x;
    ws[t] = W2[t];
    __syncthreads();
    int idx = blockIdx.x * 256 + t;
    if (idx < N * 16) {
        int n = idx >> 4, f = idx & 15;
        float sum = 0.f;
#pragma unroll
        for (int k = 0; k < 16; ++k) sum += h[(long long)n * 16 + k] * ws[k * 16 + f];
        g[idx] = sum * dinv[n];
    }
}

// out[n,:] = h[n,:] @ W_lin + b_lin   (16 -> 128), 2 nodes per block
__global__ __launch_bounds__(256) void k_final(const float* __restrict__ h,
                                               const float* __restrict__ Wl,
                                               const float* __restrict__ bl,
                                               float* __restrict__ out, int N) {
    __shared__ float ws[16 * 128];
    __shared__ float hs[2][16];
    int t = threadIdx.x;
    int n0 = blockIdx.x * 2;
    for (int idx = t; idx < 2048; idx += 256) ws[idx] = Wl[idx];
    if (t < 32) {
        int node = t >> 4, k = t & 15;
        int n = n0 + node;
        hs[node][k] = (n < N) ? h[(long long)n * 16 + k] : 0.f;
    }
    __syncthreads();
    int node = t >> 7, f = t & 127;
    int n = n0 + node;
    if (n < N) {
        float sum = bl[f];
#pragma unroll
        for (int k = 0; k < 16; ++k) sum += hs[node][k] * ws[k * 128 + f];
        out[(long long)n * 128 + f] = sum;
    }
}

extern "C" void kernel_launch(void* const* d_in, const int* in_sizes, int n_in,
                              void* d_out, int out_size, void* d_ws, size_t ws_size,
                              hipStream_t stream) {
    const float* x  = (const float*)d_in[0];
    const int*   ei = (const int*)d_in[1];
    const float* W1 = (const float*)d_in[2];
    const float* b1 = (const float*)d_in[3];
    const float* W2 = (const float*)d_in[4];
    const float* b2 = (const float*)d_in[5];
    const float* Wl = (const float*)d_in[6];
    const float* bl = (const float*)d_in[7];
    float*       out = (float*)d_out;

    const int N = in_sizes[0] / 128;
    const int E = in_sizes[1] / 2;
    const int NB = (N + NPB - 1) >> NPB_SHIFT;   // buckets actually used (<=1024)

    char* ws = (char*)d_ws;
    auto carve = [&](size_t bytes) {
        char* p = ws;
        ws += (bytes + 255) & ~(size_t)255;
        return p;
    };
    int*   bucket_cnt  = (int*)carve((size_t)NB_MAX * 4);
    int*   bucket_base = (int*)carve((size_t)NB_MAX * 4);
    int*   bucket_cur  = (int*)carve((size_t)NB_MAX * 4);
    float* dinv        = (float*)carve((size_t)N * 4);
    int*   row_start   = (int*)carve((size_t)(N + 1) * 4);
    int*   csr_src     = (int*)carve((size_t)E * 4);
    // pairs (E*8 bytes) is dead after k_build -> alias g/h onto it
    size_t union_bytes = (size_t)E * 8;
    size_t gh_bytes    = (size_t)N * 16 * 4 * 2;
    if (gh_bytes > union_bytes) union_bytes = gh_bytes;
    int2*  pairs = (int2*)carve(union_bytes);
    float* gbuf  = (float*)pairs;
    float* hbuf  = gbuf + (size_t)N * 16;
    (void)ws_size; (void)n_in; (void)out_size;

    const int TB = 256;
    // CSR build (shared by both layers)
    k_zero_buckets<<<1, NB_MAX, 0, stream>>>(bucket_cnt);
    k_bucket_cnt<<<512, TB, 0, stream>>>(ei, bucket_cnt, E);
    k_bucket_scan<<<1, NB_MAX, 0, stream>>>(bucket_cnt, bucket_base, bucket_cur);
    k_partition<<<(E + PART_TILE - 1) / PART_TILE, TB, 0, stream>>>(ei, bucket_cur, pairs, E);
    k_build<<<NB, TB, 0, stream>>>(pairs, bucket_cnt, bucket_base, row_start, dinv, csr_src, N);
    // layer 1
    k_xform1<<<(N + 15) / 16, TB, 0, stream>>>(x, W1, dinv, gbuf, N);
    k_aggr<<<(N + 3) / 4, TB, 0, stream>>>(gbuf, row_start, csr_src, dinv, b1, hbuf, N);
    // layer 2
    k_xform2<<<(N * 16 + TB - 1) / TB, TB, 0, stream>>>(hbuf, W2, dinv, gbuf, N);
    k_aggr<<<(N + 3) / 4, TB, 0, stream>>>(gbuf, row_start, csr_src, dinv, b2, hbuf, N);
    // output projection
    k_final<<<(N + 1) / 2, TB, 0, stream>>>(hbuf, Wl, bl, out, N);
}

// Round 4
// 374.621 us; speedup vs baseline: 2.6616x; 1.2915x over previous
//
#include <hip/hip_runtime.h>
#include <hip/hip_fp16.h>

// ---------------------------------------------------------------------------
// GCN forward: h1 = relu(GCNConv(x, W1, b1)); h2 = relu(GCNConv(h1, W2, b2));
// out = h2 @ W_lin + b_lin
// N=100000, E=3200000, F_in=128, H=16, F_out=128.
// edge_index arrives as int32 [2*E]: row 0 = src, row 1 = dst.
//
// R4: gathered feature array g stored in fp16 (3.2 MB -> fits 4 MB per-XCD
// L2; R3 profile showed 99.5 MB FETCH vs 26 MB ideal because fp32 g thrashed
// L2 under random gathers). csr/h streams use non-temporal hints so they
// don't evict g. Pairs packed into 32 bits (src<<7 | dst&127; valid for
// N < 2^17 -- here N=100000). Accumulation stays fp32.
// ---------------------------------------------------------------------------

typedef int   v4i __attribute__((ext_vector_type(4)));
typedef float v4f __attribute__((ext_vector_type(4)));

#define NB_MAX     1024   // max buckets (LDS hist size)
#define NPB        128    // nodes per bucket (power of 2)
#define NPB_SHIFT  7
#define PART_TILE  8192   // edges per partition block
#define PT_ITERS   (PART_TILE / 4 / 256)   // quad iterations per thread = 8

__global__ void k_zero_buckets(int* bucket_cnt) {
    bucket_cnt[threadIdx.x] = 0;
}

// Per-block LDS histogram of dst>>7, int4 loads, flushed once per block.
__global__ __launch_bounds__(256) void k_bucket_cnt(const int* __restrict__ ei,
                                                    int* __restrict__ bucket_cnt, int E) {
    __shared__ int h[NB_MAX];
    int t = threadIdx.x;
    for (int j = t; j < NB_MAX; j += 256) h[j] = 0;
    __syncthreads();
    const v4i* d4 = (const v4i*)(ei + E);
    int EQ = E >> 2;
    for (int q = blockIdx.x * 256 + t; q < EQ; q += gridDim.x * 256) {
        v4i dd = __builtin_nontemporal_load(d4 + q);
        atomicAdd(&h[dd.x >> NPB_SHIFT], 1);
        atomicAdd(&h[dd.y >> NPB_SHIFT], 1);
        atomicAdd(&h[dd.z >> NPB_SHIFT], 1);
        atomicAdd(&h[dd.w >> NPB_SHIFT], 1);
    }
    if (blockIdx.x == 0) {
        for (int e = (EQ << 2) + t; e < E; e += 256)
            atomicAdd(&h[ei[E + e] >> NPB_SHIFT], 1);
    }
    __syncthreads();
    for (int j = t; j < NB_MAX; j += 256)
        if (h[j]) atomicAdd(&bucket_cnt[j], h[j]);
}

// Exclusive scan of 1024 bucket counts; init base + cursor.
__global__ __launch_bounds__(1024) void k_bucket_scan(const int* __restrict__ bucket_cnt,
                                                      int* __restrict__ bucket_base,
                                                      int* __restrict__ bucket_cur) {
    __shared__ int s[NB_MAX];
    int t = threadIdx.x;
    int v0 = bucket_cnt[t];
    s[t] = v0;
    __syncthreads();
    for (int off = 1; off < NB_MAX; off <<= 1) {
        int v = (t >= off) ? s[t - off] : 0;
        __syncthreads();
        s[t] += v;
        __syncthreads();
    }
    int excl = s[t] - v0;
    bucket_base[t] = excl;
    bucket_cur[t]  = excl;
}

// Partition edges into bucket-contiguous packed (src<<7 | dstlocal) runs.
__global__ __launch_bounds__(256) void k_partition(const int* __restrict__ ei,
                                                   int* __restrict__ bucket_cur,
                                                   int* __restrict__ pairs, int E) {
    __shared__ int h[NB_MAX];    // pass1: local hist; pass2: local cursor
    __shared__ int rb[NB_MAX];   // run base (absolute) per bucket
    int t = threadIdx.x;
    const v4i* s4 = (const v4i*)ei;
    const v4i* d4 = (const v4i*)(ei + E);
    int EQ = E >> 2;
    int q0 = blockIdx.x * (PART_TILE / 4);
    bool last = (blockIdx.x == gridDim.x - 1);
    v4i dsave[PT_ITERS];

    for (int j = t; j < NB_MAX; j += 256) h[j] = 0;
    __syncthreads();
#pragma unroll
    for (int it = 0; it < PT_ITERS; ++it) {
        int q = q0 + it * 256 + t;
        v4i dd;
        if (q < EQ) {
            dd = __builtin_nontemporal_load(d4 + q);
            atomicAdd(&h[dd.x >> NPB_SHIFT], 1);
            atomicAdd(&h[dd.y >> NPB_SHIFT], 1);
            atomicAdd(&h[dd.z >> NPB_SHIFT], 1);
            atomicAdd(&h[dd.w >> NPB_SHIFT], 1);
        }
        dsave[it] = dd;
    }
    if (last) {
        for (int e = (EQ << 2) + t; e < E; e += 256)
            atomicAdd(&h[ei[E + e] >> NPB_SHIFT], 1);
    }
    __syncthreads();
    for (int j = t; j < NB_MAX; j += 256) {
        int c = h[j];
        rb[j] = c ? atomicAdd(&bucket_cur[j], c) : 0;
        h[j] = 0;
    }
    __syncthreads();
#pragma unroll
    for (int it = 0; it < PT_ITERS; ++it) {
        int q = q0 + it * 256 + t;
        if (q < EQ) {
            v4i ss = __builtin_nontemporal_load(s4 + q);
            v4i dd = dsave[it];
#pragma unroll
            for (int k = 0; k < 4; ++k) {
                int s = ss[k], d = dd[k];
                int b = d >> NPB_SHIFT;
                int pos = rb[b] + atomicAdd(&h[b], 1);
                pairs[pos] = (s << NPB_SHIFT) | (d & (NPB - 1));
            }
        }
    }
    if (last) {
        for (int e = (EQ << 2) + t; e < E; e += 256) {
            int s = ei[e], d = ei[E + e];
            int b = d >> NPB_SHIFT;
            int pos = rb[b] + atomicAdd(&h[b], 1);
            pairs[pos] = (s << NPB_SHIFT) | (d & (NPB - 1));
        }
    }
}

// One block per bucket: local deg hist -> local scan -> row_start/dinv,
// then scatter csr_src within the bucket's contiguous region.
__global__ __launch_bounds__(256) void k_build(const int* __restrict__ pairs,
                                               const int* __restrict__ bucket_cnt,
                                               const int* __restrict__ bucket_base,
                                               int* __restrict__ row_start,
                                               float* __restrict__ dinv,
                                               int* __restrict__ csr_src, int N) {
    __shared__ int deg[NPB];
    __shared__ int scn[NPB];
    __shared__ int cur[NPB];
    int b = blockIdx.x, t = threadIdx.x;
    int n0 = b << NPB_SHIFT;
    int cnt  = bucket_cnt[b];
    int base = bucket_base[b];
    if (t < NPB) deg[t] = 0;
    __syncthreads();
    for (int i = t; i < cnt; i += 256)
        atomicAdd(&deg[pairs[base + i] & (NPB - 1)], 1);
    __syncthreads();
    if (t < NPB) scn[t] = deg[t];
    __syncthreads();
    for (int off = 1; off < NPB; off <<= 1) {
        int v = (t < NPB && t >= off) ? scn[t - off] : 0;
        __syncthreads();
        if (t < NPB) scn[t] += v;
        __syncthreads();
    }
    if (t < NPB) {
        int n = n0 + t;
        if (n < N) {
            int excl = scn[t] - deg[t];
            row_start[n] = base + excl;
            cur[t]       = base + excl;
            dinv[n]      = rsqrtf((float)(deg[t] + 1));  // +1 self-loop
        }
    }
    if (t == 0 && b == gridDim.x - 1) row_start[N] = base + cnt;
    __syncthreads();
    for (int i = t; i < cnt; i += 256) {
        int p = pairs[base + i];
        int pos = atomicAdd(&cur[p & (NPB - 1)], 1);
        csr_src[pos] = p >> NPB_SHIFT;
    }
}

// g[n,:] = fp16( (x[n,:] @ W1) * dinv[n] )   (128 -> 16), 16 nodes per block
__global__ __launch_bounds__(256) void k_xform1(const float* __restrict__ x,
                                                const float* __restrict__ W1,
                                                const float* __restrict__ dinv,
                                                __half* __restrict__ g, int N) {
    __shared__ float xs[16][132];   // stride 132: float4-aligned, conflict-free
    __shared__ float ws[128 * 16];
    int t = threadIdx.x;
    int n0 = blockIdx.x * 16;
    const v4f* w4 = (const v4f*)W1;
    const v4f* x4 = (const v4f*)x;
    for (int idx = t; idx < 512; idx += 256) ((v4f*)ws)[idx] = w4[idx];
    for (int idx = t; idx < 512; idx += 256) {
        int r = idx >> 5, c4 = idx & 31;
        int n = n0 + r;
        v4f v = (n < N) ? x4[(size_t)n * 32 + c4] : (v4f)(0.f);
        *(v4f*)&xs[r][c4 * 4] = v;
    }
    __syncthreads();
    int node = t >> 4, f = t & 15;
    int n = n0 + node;
    if (n < N) {
        float sum = 0.f;
#pragma unroll
        for (int k = 0; k < 128; ++k) sum += xs[node][k] * ws[k * 16 + f];
        g[(size_t)n * 16 + f] = __float2half_rn(sum * dinv[n]);
    }
}

// h[d,:] = relu( dinv[d] * (sum_{s in row d} g[s,:] + g[d,:]) + bias )
// one wave per node: 8 edge-groups x 8 half2-feature lanes.
// csr stream + h store are non-temporal so g stays L2-resident.
__global__ __launch_bounds__(256) void k_aggr(const __half* __restrict__ g,
                                              const int* __restrict__ row_start,
                                              const int* __restrict__ csr_src,
                                              const float* __restrict__ dinv,
                                              const float* __restrict__ bias,
                                              float* __restrict__ h, int N) {
    int wave = threadIdx.x >> 6;
    int lane = threadIdx.x & 63;
    int d = blockIdx.x * 4 + wave;
    if (d >= N) return;
    int grp = lane >> 3, f2 = lane & 7;
    int s0 = row_start[d], s1 = row_start[d + 1];
    float sx = 0.f, sy = 0.f;
    for (int i = s0 + grp; i < s1; i += 8) {
        int s = __builtin_nontemporal_load(csr_src + i);
        float2 fv = __half22float2(*(const __half2*)(g + (size_t)s * 16 + 2 * f2));
        sx += fv.x;
        sy += fv.y;
    }
    sx += __shfl_xor(sx, 8);  sy += __shfl_xor(sy, 8);
    sx += __shfl_xor(sx, 16); sy += __shfl_xor(sy, 16);
    sx += __shfl_xor(sx, 32); sy += __shfl_xor(sy, 32);
    if (grp == 0) {
        float2 self = __half22float2(*(const __half2*)(g + (size_t)d * 16 + 2 * f2));
        float di = dinv[d];
        float bx = bias[2 * f2], by = bias[2 * f2 + 1];
        float ox = fmaxf(di * (sx + self.x) + bx, 0.f);
        float oy = fmaxf(di * (sy + self.y) + by, 0.f);
        __builtin_nontemporal_store(ox, h + (size_t)d * 16 + 2 * f2);
        __builtin_nontemporal_store(oy, h + (size_t)d * 16 + 2 * f2 + 1);
    }
}

// g[n,:] = fp16( (h[n,:] @ W2) * dinv[n] )   (16 -> 16), half2 per thread
__global__ __launch_bounds__(256) void k_xform2(const float* __restrict__ h,
                                                const float* __restrict__ W2,
                                                const float* __restrict__ dinv,
                                                __half* __restrict__ g, int N) {
    __shared__ float ws[256];
    int t = threadIdx.x;
    ws[t] = W2[t];
    __syncthreads();
    int idx = blockIdx.x * 256 + t;
    if (idx < N * 8) {
        int n = idx >> 3, f2 = idx & 7;
        float sx = 0.f, sy = 0.f;
#pragma unroll
        for (int k = 0; k < 16; ++k) {
            float hv = h[(size_t)n * 16 + k];
            sx += hv * ws[k * 16 + 2 * f2];
            sy += hv * ws[k * 16 + 2 * f2 + 1];
        }
        float di = dinv[n];
        *(__half2*)(g + (size_t)n * 16 + 2 * f2) = __floats2half2_rn(sx * di, sy * di);
    }
}

// out[n,:] = h[n,:] @ W_lin + b_lin   (16 -> 128), 8 nodes/block, float4 out
__global__ __launch_bounds__(256) void k_final(const float* __restrict__ h,
                                               const float* __restrict__ Wl,
                                               const float* __restrict__ bl,
                                               float* __restrict__ out, int N) {
    __shared__ float ws[16 * 128];
    __shared__ float hs[8][16];
    int t = threadIdx.x;
    int n0 = blockIdx.x * 8;
    const v4f* w4 = (const v4f*)Wl;
    for (int idx = t; idx < 512; idx += 256) ((v4f*)ws)[idx] = w4[idx];
    if (t < 128) {
        int node = t >> 4, k = t & 15;
        int n = n0 + node;
        hs[node][k] = (n < N) ? h[(size_t)n * 16 + k] : 0.f;
    }
    __syncthreads();
    int node = t >> 5, f4 = t & 31;
    int n = n0 + node;
    if (n < N) {
        v4f acc = *(const v4f*)(bl + 4 * f4);
#pragma unroll
        for (int k = 0; k < 16; ++k) {
            float hv = hs[node][k];
            acc += hv * *((const v4f*)&ws[k * 128 + 4 * f4]);
        }
        __builtin_nontemporal_store(acc, (v4f*)(out + (size_t)n * 128 + 4 * f4));
    }
}

extern "C" void kernel_launch(void* const* d_in, const int* in_sizes, int n_in,
                              void* d_out, int out_size, void* d_ws, size_t ws_size,
                              hipStream_t stream) {
    const float* x  = (const float*)d_in[0];
    const int*   ei = (const int*)d_in[1];
    const float* W1 = (const float*)d_in[2];
    const float* b1 = (const float*)d_in[3];
    const float* W2 = (const float*)d_in[4];
    const float* b2 = (const float*)d_in[5];
    const float* Wl = (const float*)d_in[6];
    const float* bl = (const float*)d_in[7];
    float*       out = (float*)d_out;

    const int N = in_sizes[0] / 128;
    const int E = in_sizes[1] / 2;
    const int NB = (N + NPB - 1) >> NPB_SHIFT;   // buckets used (<=1024)

    char* ws = (char*)d_ws;
    auto carve = [&](size_t bytes) {
        char* p = ws;
        ws += (bytes + 255) & ~(size_t)255;
        return p;
    };
    int*   bucket_cnt  = (int*)carve((size_t)NB_MAX * 4);
    int*   bucket_base = (int*)carve((size_t)NB_MAX * 4);
    int*   bucket_cur  = (int*)carve((size_t)NB_MAX * 4);
    float* dinv        = (float*)carve((size_t)N * 4);
    int*   row_start   = (int*)carve((size_t)(N + 1) * 4);
    int*   csr_src     = (int*)carve((size_t)E * 4);
    // pairs (E*4 B packed) dead after k_build -> alias g(fp16)+h(fp32) onto it
    size_t gh_bytes    = (size_t)N * 16 * 2 + (size_t)N * 16 * 4;
    size_t union_bytes = (size_t)E * 4;
    if (gh_bytes > union_bytes) union_bytes = gh_bytes;
    int*    pairs = (int*)carve(union_bytes);
    __half* gbuf  = (__half*)pairs;
    float*  hbuf  = (float*)((char*)pairs + ((size_t)N * 16 * 2 + 255 & ~(size_t)255));
    (void)ws_size; (void)n_in; (void)out_size;

    const int TB = 256;
    // CSR build (shared by both layers)
    k_zero_buckets<<<1, NB_MAX, 0, stream>>>(bucket_cnt);
    k_bucket_cnt<<<512, TB, 0, stream>>>(ei, bucket_cnt, E);
    k_bucket_scan<<<1, NB_MAX, 0, stream>>>(bucket_cnt, bucket_base, bucket_cur);
    k_partition<<<(E + PART_TILE - 1) / PART_TILE, TB, 0, stream>>>(ei, bucket_cur, pairs, E);
    k_build<<<NB, TB, 0, stream>>>(pairs, bucket_cnt, bucket_base, row_start, dinv, csr_src, N);
    // layer 1
    k_xform1<<<(N + 15) / 16, TB, 0, stream>>>(x, W1, dinv, gbuf, N);
    k_aggr<<<(N + 3) / 4, TB, 0, stream>>>(gbuf, row_start, csr_src, dinv, b1, hbuf, N);
    // layer 2
    k_xform2<<<(N * 8 + TB - 1) / TB, TB, 0, stream>>>(hbuf, W2, dinv, gbuf, N);
    k_aggr<<<(N + 3) / 4, TB, 0, stream>>>(gbuf, row_start, csr_src, dinv, b2, hbuf, N);
    // output projection
    k_final<<<(N + 7) / 8, TB, 0, stream>>>(hbuf, Wl, bl, out, N);
}